// Round 9
// baseline (179.590 us; speedup 1.0000x reference)
//
#include <hip/hip_runtime.h>
#include <math.h>

#define B 8192
#define D 128
#define C 1000
#define EPS 1e-6f
#define LAMBD 0.1f

// ws layout (float slots):
// [0] ce_acc [1] feat_acc
// [2        .. 2+B)    dtot[i]            (memset 0 with ce/feat)
// [2+B      .. 2+2B)   e[i] = sq+2*EPS*s
// [2+2B     .. 2+3B)   f[j] = sq-2*EPS*s
// [2+3B     .. 2+4B)   dpos[i]
// [2+4B     .. +C)     fo[c] as unsigned  (memset 0xFF; unsigned atomicMin)
// [33792    .. +B*64)  xbf: x as bf16, per-row XOR-swizzled 16B chunks
#define OFF_DTOT 2
#define OFF_E (2 + B)
#define OFF_F (2 + 2 * B)
#define OFF_DPOS (2 + 3 * B)
#define OFF_FO (2 + 4 * B)
#define OFF_XBF 33792

typedef __attribute__((ext_vector_type(8))) short short8;
typedef __attribute__((ext_vector_type(4))) float floatx4;

__device__ inline unsigned short f2bf(float f) {
    union { float f; unsigned u; } v; v.f = f;
    unsigned u = v.u;
    return (unsigned short)((u + 0x7fffu + ((u >> 16) & 1u)) >> 16);  // RTNE
}

// one wave per row: stats + bf16 swizzled copy of x
__global__ void __launch_bounds__(256)
k_rowstats(const float* __restrict__ x, const int* __restrict__ y, float* ws) {
    int row = blockIdx.x * 4 + (threadIdx.x >> 6);
    int lane = threadIdx.x & 63;
    const float2* x2 = (const float2*)x;
    float2 v = x2[row * 64 + lane];  // elements 2*lane, 2*lane+1
    float sq = v.x * v.x + v.y * v.y;
    float s = v.x + v.y;
    for (int o = 32; o; o >>= 1) {
        sq += __shfl_xor(sq, o);
        s += __shfl_xor(s, o);
    }
    // bf16 store, chunk (16B) index XOR-swizzled with (row&7)
    ushort2 p = { f2bf(v.x), f2bf(v.y) };
    ushort2* xrow = (ushort2*)((unsigned short*)(ws + OFF_XBF) + row * 128);
    xrow[(((lane >> 2) ^ (row & 7)) << 2) + (lane & 3)] = p;
    if (lane == 0) {
        ws[OFF_E + row] = sq + 2.f * EPS * s;
        ws[OFF_F + row] = sq - 2.f * EPS * s;
        atomicMin((unsigned*)(ws + OFF_FO) + y[row], (unsigned)row);
    }
}

// wave-per-row CE: 4 rows / 256-thread block, no barriers in the hot path.
__global__ void __launch_bounds__(256)
k_ce(const float* __restrict__ data, const int* __restrict__ y, float* ws) {
    int row = blockIdx.x * 4 + (threadIdx.x >> 6);
    int lane = threadIdx.x & 63;
    const float* dr = data + (size_t)row * C;
    const float4* dr4 = (const float4*)dr;  // row*4000B is 16B-aligned

    float4 v[4];
    float m = -1e30f;
#pragma unroll
    for (int k = 0; k < 4; k++) {
        int idx = k * 64 + lane;
        if (idx < C / 4) {
            v[k] = dr4[idx];
            m = fmaxf(fmaxf(fmaxf(m, v[k].x), fmaxf(v[k].y, v[k].z)), v[k].w);
        }
    }
    for (int o = 32; o; o >>= 1) m = fmaxf(m, __shfl_xor(m, o));

    float sum = 0.f;
#pragma unroll
    for (int k = 0; k < 4; k++) {
        int idx = k * 64 + lane;
        if (idx < C / 4) {
            sum += __expf(v[k].x - m) + __expf(v[k].y - m) +
                   __expf(v[k].z - m) + __expf(v[k].w - m);
        }
    }
    for (int o = 32; o; o >>= 1) sum += __shfl_xor(sum, o);

    __shared__ float sp[4];
    if (lane == 0) {
        float lse = m + __logf(sum);
        sp[threadIdx.x >> 6] = lse - dr[y[row]];
    }
    __syncthreads();
    if (threadIdx.x == 0)
        atomicAdd(ws + 0, sp[0] + sp[1] + sp[2] + sp[3]);
}

__global__ void k_dpos(const float* __restrict__ x, const int* __restrict__ y,
                       float* ws) {
    int row = blockIdx.x * 4 + (threadIdx.x >> 6);
    int lane = threadIdx.x & 63;
    const unsigned* fo = (const unsigned*)(ws + OFF_FO);
    int fp = (int)fo[y[row]];
    float d0 = x[row * D + lane] - x[fp * D + lane] + EPS;
    float d1 = x[row * D + 64 + lane] - x[fp * D + 64 + lane] + EPS;
    float sq = d0 * d0 + d1 * d1;
    for (int o = 32; o; o >>= 1) sq += __shfl_xor(sq, o);
    if (lane == 0) ws[OFF_DPOS + row] = sqrtf(sq);
}

// Gram + dist + row/col sums via MFMA, upper-triangle blocks only (j >= i).
// Staging is a pure linear bf16 copy (source is pre-swizzled by k_rowstats).
__global__ void __launch_bounds__(256)
k_gram_dtot(float* ws) {
    int bj = blockIdx.x, bi = blockIdx.y;
    if (bj < bi) return;
    bool offdiag = (bj != bi);

    __shared__ alignas(16) short lA[128 * 128];
    __shared__ alignas(16) short lB[128 * 128];
    __shared__ float sdrow[128];
    __shared__ float sdcol[128];
    int t = threadIdx.x;
    int i0 = bi * 128, j0 = bj * 128;

    const short8* xb8 = (const short8*)(ws + OFF_XBF);  // 16 chunks/row
#pragma unroll
    for (int it = 0; it < 8; ++it) {
        int idx = it * 256 + t;  // 0..2047 chunks of the 128-row panel
        ((short8*)lA)[idx] = xb8[i0 * 16 + idx];
        ((short8*)lB)[idx] = xb8[j0 * 16 + idx];
    }
    if (t < 128) { sdrow[t] = 0.f; sdcol[t] = 0.f; }
    __syncthreads();

    int lane = t & 63, wid = t >> 6;
    int wm = wid >> 1, wn = wid & 1;
    int lo = lane & 15, hi = lane >> 4;

    floatx4 acc[4][4];
#pragma unroll
    for (int mr = 0; mr < 4; ++mr)
#pragma unroll
        for (int nr = 0; nr < 4; ++nr) acc[mr][nr] = (floatx4){0.f, 0.f, 0.f, 0.f};

#pragma unroll
    for (int kt = 0; kt < 4; ++kt) {
        short8 af[4], bg[4];
        int ch = kt * 4 + hi;
#pragma unroll
        for (int mr = 0; mr < 4; ++mr) {
            int r = wm * 64 + mr * 16 + lo;
            af[mr] = *(const short8*)&lA[r * 128 + ((ch ^ (r & 7)) << 3)];
        }
#pragma unroll
        for (int nr = 0; nr < 4; ++nr) {
            int r = wn * 64 + nr * 16 + lo;
            bg[nr] = *(const short8*)&lB[r * 128 + ((ch ^ (r & 7)) << 3)];
        }
#pragma unroll
        for (int mr = 0; mr < 4; ++mr)
#pragma unroll
            for (int nr = 0; nr < 4; ++nr)
                acc[mr][nr] = __builtin_amdgcn_mfma_f32_16x16x32_bf16(
                    af[mr], bg[nr], acc[mr][nr], 0, 0, 0);
    }

    const float* e = ws + OFF_E;
    const float* f = ws + OFF_F;
    float* dtot = ws + OFF_DTOT;
    const float deps2 = (float)D * EPS * EPS;

    float er[4][4];
#pragma unroll
    for (int mr = 0; mr < 4; ++mr)
#pragma unroll
        for (int rg = 0; rg < 4; ++rg)
            er[mr][rg] = e[i0 + wm * 64 + mr * 16 + hi * 4 + rg] + deps2;
    float fc[4];
#pragma unroll
    for (int nr = 0; nr < 4; ++nr) fc[nr] = f[j0 + wn * 64 + nr * 16 + lo];

    float rs[4][4], cs[4];
#pragma unroll
    for (int mr = 0; mr < 4; ++mr)
#pragma unroll
        for (int rg = 0; rg < 4; ++rg) rs[mr][rg] = 0.f;
#pragma unroll
    for (int nr = 0; nr < 4; ++nr) cs[nr] = 0.f;

#pragma unroll
    for (int mr = 0; mr < 4; ++mr)
#pragma unroll
        for (int nr = 0; nr < 4; ++nr)
#pragma unroll
            for (int rg = 0; rg < 4; ++rg) {
                float d2 = er[mr][rg] + fc[nr] - 2.f * acc[mr][nr][rg];
                float d = sqrtf(fmaxf(d2, 0.f));
                rs[mr][rg] += d;
                cs[nr] += d;
            }

#pragma unroll
    for (int mr = 0; mr < 4; ++mr)
#pragma unroll
        for (int rg = 0; rg < 4; ++rg) {
            float v = rs[mr][rg];
            v += __shfl_xor(v, 1);
            v += __shfl_xor(v, 2);
            v += __shfl_xor(v, 4);
            v += __shfl_xor(v, 8);
            if (lo == 0) atomicAdd(&sdrow[wm * 64 + mr * 16 + hi * 4 + rg], v);
        }
    if (offdiag) {
#pragma unroll
        for (int nr = 0; nr < 4; ++nr) {
            float v = cs[nr];
            v += __shfl_xor(v, 16);
            v += __shfl_xor(v, 32);
            if (hi == 0) atomicAdd(&sdcol[wn * 64 + nr * 16 + lo], v);
        }
    }
    __syncthreads();
    if (t < 128) {
        atomicAdd(&dtot[i0 + t], sdrow[t]);
        if (offdiag) atomicAdd(&dtot[j0 + t], sdcol[t]);
    }
}

// fused feature-loss reduce + final output (single block)
__global__ void __launch_bounds__(1024)
k_featout(const float* __restrict__ ws, float* __restrict__ out) {
    int t = threadIdx.x;
    const float* dtot = ws + OFF_DTOT;
    const float* dpos = ws + OFF_DPOS;
    float r = 0.f;
#pragma unroll
    for (int k = 0; k < B / 1024; k++) {
        int i = k * 1024 + t;
        float dp = dpos[i], dt = dtot[i];
        r += dp / (dt - dp);
    }
    for (int o = 32; o; o >>= 1) r += __shfl_xor(r, o);
    __shared__ float sm[16];
    if ((t & 63) == 0) sm[t >> 6] = r;
    __syncthreads();
    if (t == 0) {
        float lf = 0.f;
#pragma unroll
        for (int w = 0; w < 16; w++) lf += sm[w];
        float la = ws[0] / (float)B;
        out[0] = la + LAMBD * lf;
        out[1] = la;
        out[2] = lf;
    }
}

extern "C" void kernel_launch(void* const* d_in, const int* in_sizes, int n_in,
                              void* d_out, int out_size, void* d_ws, size_t ws_size,
                              hipStream_t stream) {
    const float* data = (const float*)d_in[0];
    const float* x = (const float*)d_in[1];
    const int* y = (const int*)d_in[2];
    float* out = (float*)d_out;
    float* ws = (float*)d_ws;

    (void)hipMemsetAsync(ws, 0, (2 + B) * sizeof(float), stream);          // ce/feat/dtot
    (void)hipMemsetAsync(ws + OFF_FO, 0xFF, C * sizeof(unsigned), stream); // fo
    k_rowstats<<<B / 4, 256, 0, stream>>>(x, y, ws);
    k_ce<<<B / 4, 256, 0, stream>>>(data, y, ws);
    k_dpos<<<B / 4, 256, 0, stream>>>(x, y, ws);
    k_gram_dtot<<<dim3(64, 64), 256, 0, stream>>>(ws);
    k_featout<<<1, 1024, 0, stream>>>(ws, out);
}

// Round 10
// 152.481 us; speedup vs baseline: 1.1778x; 1.1778x over previous
//
#include <hip/hip_runtime.h>
#include <math.h>

#define B 8192
#define D 128
#define C 1000
#define EPS 1e-6f
#define LAMBD 0.1f

// ws layout (float slots):
// [0] ce_acc [1] feat_acc
// [2        .. 2+B)    dtot[i]            (memset 0 with ce/feat)
// [2+B      .. 2+2B)   e[i] = sq+2*EPS*s
// [2+2B     .. 2+3B)   f[j] = sq-2*EPS*s
// [2+3B     .. 2+4B)   dpos[i]
// [2+4B     .. +C)     fo[c] as unsigned  (memset 0xFF; unsigned atomicMin)
// [33792    .. +B*64)  xbf: x as bf16, per-row XOR-swizzled 16B chunks
#define OFF_DTOT 2
#define OFF_E (2 + B)
#define OFF_F (2 + 2 * B)
#define OFF_DPOS (2 + 3 * B)
#define OFF_FO (2 + 4 * B)
#define OFF_XBF 33792

typedef __attribute__((ext_vector_type(8))) short short8;
typedef __attribute__((ext_vector_type(4))) float floatx4;

__device__ inline unsigned short f2bf(float f) {
    union { float f; unsigned u; } v; v.f = f;
    unsigned u = v.u;
    return (unsigned short)((u + 0x7fffu + ((u >> 16) & 1u)) >> 16);  // RTNE
}

// one wave per row: stats + bf16 swizzled copy of x
__global__ void __launch_bounds__(256)
k_rowstats(const float* __restrict__ x, const int* __restrict__ y, float* ws) {
    int row = blockIdx.x * 4 + (threadIdx.x >> 6);
    int lane = threadIdx.x & 63;
    const float2* x2 = (const float2*)x;
    float2 v = x2[row * 64 + lane];  // elements 2*lane, 2*lane+1
    float sq = v.x * v.x + v.y * v.y;
    float s = v.x + v.y;
    for (int o = 32; o; o >>= 1) {
        sq += __shfl_xor(sq, o);
        s += __shfl_xor(s, o);
    }
    // bf16 store, chunk (16B) index XOR-swizzled with (row&7)
    ushort2 p = { f2bf(v.x), f2bf(v.y) };
    ushort2* xrow = (ushort2*)((unsigned short*)(ws + OFF_XBF) + row * 128);
    xrow[(((lane >> 2) ^ (row & 7)) << 2) + (lane & 3)] = p;
    if (lane == 0) {
        ws[OFF_E + row] = sq + 2.f * EPS * s;
        ws[OFF_F + row] = sq - 2.f * EPS * s;
        atomicMin((unsigned*)(ws + OFF_FO) + y[row], (unsigned)row);
    }
}

// wave-per-row CE: 4 rows / 256-thread block, no barriers in the hot path.
__global__ void __launch_bounds__(256)
k_ce(const float* __restrict__ data, const int* __restrict__ y, float* ws) {
    int row = blockIdx.x * 4 + (threadIdx.x >> 6);
    int lane = threadIdx.x & 63;
    const float* dr = data + (size_t)row * C;
    const float4* dr4 = (const float4*)dr;  // row*4000B is 16B-aligned

    float4 v[4];
    float m = -1e30f;
#pragma unroll
    for (int k = 0; k < 4; k++) {
        int idx = k * 64 + lane;
        if (idx < C / 4) {
            v[k] = dr4[idx];
            m = fmaxf(fmaxf(fmaxf(m, v[k].x), fmaxf(v[k].y, v[k].z)), v[k].w);
        }
    }
    for (int o = 32; o; o >>= 1) m = fmaxf(m, __shfl_xor(m, o));

    float sum = 0.f;
#pragma unroll
    for (int k = 0; k < 4; k++) {
        int idx = k * 64 + lane;
        if (idx < C / 4) {
            sum += __expf(v[k].x - m) + __expf(v[k].y - m) +
                   __expf(v[k].z - m) + __expf(v[k].w - m);
        }
    }
    for (int o = 32; o; o >>= 1) sum += __shfl_xor(sum, o);

    __shared__ float sp[4];
    if (lane == 0) {
        float lse = m + __logf(sum);
        sp[threadIdx.x >> 6] = lse - dr[y[row]];
    }
    __syncthreads();
    if (threadIdx.x == 0)
        atomicAdd(ws + 0, sp[0] + sp[1] + sp[2] + sp[3]);
}

__global__ void k_dpos(const float* __restrict__ x, const int* __restrict__ y,
                       float* ws) {
    int row = blockIdx.x * 4 + (threadIdx.x >> 6);
    int lane = threadIdx.x & 63;
    const unsigned* fo = (const unsigned*)(ws + OFF_FO);
    int fp = (int)fo[y[row]];
    float d0 = x[row * D + lane] - x[fp * D + lane] + EPS;
    float d1 = x[row * D + 64 + lane] - x[fp * D + 64 + lane] + EPS;
    float sq = d0 * d0 + d1 * d1;
    for (int o = 32; o; o >>= 1) sq += __shfl_xor(sq, o);
    if (lane == 0) ws[OFF_DPOS + row] = sqrtf(sq);
}

// Gram + dist + row/col sums via MFMA. Register-resident, LDS-free, no barriers.
// Triangular pairing: pair p = {band p, band 63-p} has 65 j-tiles total;
// 16 sub-blocks per pair take strided shares -> 512 blocks, ~4 tiles each.
// A-frags loaded once per band into regs; B-frags streamed from L2 (xbf = 2MB).
__global__ void __launch_bounds__(256, 2)
k_gram_dtot(float* ws) {
    const int t = threadIdx.x;
    const int lane = t & 63, wid = t >> 6;
    const int wm = wid >> 1, wn = wid & 1;
    const int lo = lane & 15, hi = lane >> 4;
    const int p = blockIdx.x >> 4;    // pair 0..31
    const int sub = blockIdx.x & 15;  // 0..15
    const int b0 = p, b1 = 63 - p;
    const int n0 = 64 - b0;

    const short8* __restrict__ xb8 = (const short8*)(ws + OFF_XBF);
    const float* __restrict__ e = ws + OFF_E;
    const float* __restrict__ f = ws + OFF_F;
    float* dtot = ws + OFF_DTOT;
    const float deps2 = (float)D * EPS * EPS;
    const int swz = lo & 7;

    short8 af[4][4];  // [kt][mr]
    float er[4][4], rs[4][4];
    int cur_band = -1;

#define FLUSH_RS()                                                            \
    {                                                                         \
        _Pragma("unroll") for (int mr = 0; mr < 4; ++mr)                      \
            _Pragma("unroll") for (int rg = 0; rg < 4; ++rg) {                \
            float v = rs[mr][rg];                                             \
            v += __shfl_xor(v, 1);                                            \
            v += __shfl_xor(v, 2);                                            \
            v += __shfl_xor(v, 4);                                            \
            v += __shfl_xor(v, 8);                                            \
            if (lo == 0)                                                      \
                atomicAdd(&dtot[cur_band * 128 + wm * 64 + mr * 16 + hi * 4 + rg], v); \
        }                                                                     \
    }

    for (int q = sub; q < 65; q += 16) {
        int band = (q < n0) ? b0 : b1;
        int j = (q < n0) ? b0 + q : b1 + (q - n0);

        if (band != cur_band) {
            if (cur_band >= 0) FLUSH_RS();
            cur_band = band;
#pragma unroll
            for (int mr = 0; mr < 4; ++mr) {
                int r = band * 128 + wm * 64 + mr * 16 + lo;
#pragma unroll
                for (int kt = 0; kt < 4; ++kt)
                    af[kt][mr] = xb8[r * 16 + ((kt * 4 + hi) ^ swz)];
#pragma unroll
                for (int rg = 0; rg < 4; ++rg) {
                    er[mr][rg] =
                        e[band * 128 + wm * 64 + mr * 16 + hi * 4 + rg] + deps2;
                    rs[mr][rg] = 0.f;
                }
            }
        }

        const int jr = j * 128 + wn * 64;
        float fc[4];
#pragma unroll
        for (int nr = 0; nr < 4; ++nr) fc[nr] = f[jr + nr * 16 + lo];

        floatx4 acc[4][4];
#pragma unroll
        for (int mr = 0; mr < 4; ++mr)
#pragma unroll
            for (int nr = 0; nr < 4; ++nr)
                acc[mr][nr] = (floatx4){0.f, 0.f, 0.f, 0.f};

#pragma unroll
        for (int kt = 0; kt < 4; ++kt) {
            short8 bg[4];
#pragma unroll
            for (int nr = 0; nr < 4; ++nr) {
                int r = jr + nr * 16 + lo;
                bg[nr] = xb8[r * 16 + ((kt * 4 + hi) ^ swz)];
            }
#pragma unroll
            for (int mr = 0; mr < 4; ++mr)
#pragma unroll
                for (int nr = 0; nr < 4; ++nr)
                    acc[mr][nr] = __builtin_amdgcn_mfma_f32_16x16x32_bf16(
                        af[kt][mr], bg[nr], acc[mr][nr], 0, 0, 0);
        }

        float cs[4] = {0.f, 0.f, 0.f, 0.f};
#pragma unroll
        for (int mr = 0; mr < 4; ++mr)
#pragma unroll
            for (int nr = 0; nr < 4; ++nr)
#pragma unroll
                for (int rg = 0; rg < 4; ++rg) {
                    float d2 = fmaf(-2.f, acc[mr][nr][rg], er[mr][rg]) + fc[nr];
                    float pp = fmaxf(d2, deps2);
                    float d = pp * __frsqrt_rn(pp);  // sqrt via v_rsq
                    rs[mr][rg] += d;
                    cs[nr] += d;
                }

        if (j != band) {
#pragma unroll
            for (int nr = 0; nr < 4; ++nr) {
                float v = cs[nr];
                v += __shfl_xor(v, 16);
                v += __shfl_xor(v, 32);
                if (hi == 0) atomicAdd(&dtot[jr + nr * 16 + lo], v);
            }
        }
    }
    if (cur_band >= 0) FLUSH_RS();
#undef FLUSH_RS
}

// fused feature-loss reduce + final output (single block)
__global__ void __launch_bounds__(1024)
k_featout(const float* __restrict__ ws, float* __restrict__ out) {
    int t = threadIdx.x;
    const float* dtot = ws + OFF_DTOT;
    const float* dpos = ws + OFF_DPOS;
    float r = 0.f;
#pragma unroll
    for (int k = 0; k < B / 1024; k++) {
        int i = k * 1024 + t;
        float dp = dpos[i], dt = dtot[i];
        r += dp / (dt - dp);
    }
    for (int o = 32; o; o >>= 1) r += __shfl_xor(r, o);
    __shared__ float sm[16];
    if ((t & 63) == 0) sm[t >> 6] = r;
    __syncthreads();
    if (t == 0) {
        float lf = 0.f;
#pragma unroll
        for (int w = 0; w < 16; w++) lf += sm[w];
        float la = ws[0] / (float)B;
        out[0] = la + LAMBD * lf;
        out[1] = la;
        out[2] = lf;
    }
}

extern "C" void kernel_launch(void* const* d_in, const int* in_sizes, int n_in,
                              void* d_out, int out_size, void* d_ws, size_t ws_size,
                              hipStream_t stream) {
    const float* data = (const float*)d_in[0];
    const float* x = (const float*)d_in[1];
    const int* y = (const int*)d_in[2];
    float* out = (float*)d_out;
    float* ws = (float*)d_ws;

    (void)hipMemsetAsync(ws, 0, (2 + B) * sizeof(float), stream);          // ce/feat/dtot
    (void)hipMemsetAsync(ws + OFF_FO, 0xFF, C * sizeof(unsigned), stream); // fo
    k_rowstats<<<B / 4, 256, 0, stream>>>(x, y, ws);
    k_ce<<<B / 4, 256, 0, stream>>>(data, y, ws);
    k_dpos<<<B / 4, 256, 0, stream>>>(x, y, ws);
    k_gram_dtot<<<512, 256, 0, stream>>>(ws);
    k_featout<<<1, 1024, 0, stream>>>(ws, out);
}